// Round 1
// baseline (78.481 us; speedup 1.0000x reference)
//
#include <hip/hip_runtime.h>

// SKANLinear: y[b,o] = sum_{i=0}^{IN} weight[o,i] * sin(w[o,i] * x_ext[b,i])
// x_ext[b,IN] = 1.0. B=2048, IN=256, OUT=256. f32.
//
// R5 structure change vs R4: kill the scalar-pipe (SMEM) coefficient stream.
//  R4 fed w/g via s_load batches; SMEM is out-of-order + shares lgkmcnt with
//  the ds_read x-copy -> conservative lgkmcnt(0) stalls dominated (~3.5x over
//  the VALU floor). Now w/g are staged per-chunk into LDS packed as
//  {w0,g0,w1,g1} 16B rows per (i,wave): the inner loop reads them with ONE
//  uniform-address ds_read_b128 (broadcast, bank-free) + one per-lane
//  ds_read_b32 for x. lgkmcnt is DS-only (in-order) -> compiler emits deep
//  counted waits. No SMEM, no xs[64] reg copy (-64 VGPRs).
//  Double-buffered LDS, ONE barrier per chunk: stage(c+1) issues its global
//  loads before compute(c), so HBM/L2 latency hides under the sin chain.
// LDS 22.0 KB. Grid 1024 = 4 blocks/CU resident, 4 waves/SIMD.
// Inner loop cost/lane/i: 2 mul + 2 sin + 2 fma = 24 cyc (sin quarter-rate).

#define IN_DIM 256
#define OUT_DIM 256
#define LDW 257
#define CHUNK 32
#define NCHUNK 8            // 256 / 32
#define LXS 33              // x tile row stride (odd -> 2-way bank alias = free)
#define WGS 20              // wg row stride floats (80 B: keeps 16B slot align)
#define INV_2PI 0.15915494309189535f

__global__ __launch_bounds__(256, 4)
void skan_kernel(const float* __restrict__ x,      // [2048][256]
                 const float* __restrict__ weight, // [256][257]
                 const float* __restrict__ wfreq,  // [256][257]
                 float* __restrict__ y)            // [2048][256]
{
    __shared__ __align__(16) float lx[2][64 * LXS];     // x * INV_2PI, transposed access
    __shared__ __align__(16) float wg[2][CHUNK * WGS];  // [i][{w0,g0,w1,g1} per wave]

    const int t  = threadIdx.x;
    const int l  = t & 63;                                   // lane = local b
    const int wv = __builtin_amdgcn_readfirstlane(t >> 6);   // wave id, uniform

    const int obase = (blockIdx.x & 31) * 8;
    const int b0    = (blockIdx.x >> 5) * 64;

    const int o0 = obase + wv * 2;

    // bias column (i=256, x_ext=1): every lane owns a full (b,o) sum -> init acc.
    const float* w0r = wfreq  + o0 * LDW;
    const float* g0r = weight + o0 * LDW;
    const float* w1r = wfreq  + (o0 + 1) * LDW;
    const float* g1r = weight + (o0 + 1) * LDW;
    float acc0 = g0r[IN_DIM] * __builtin_amdgcn_sinf(w0r[IN_DIM] * INV_2PI);
    float acc1 = g1r[IN_DIM] * __builtin_amdgcn_sinf(w1r[IN_DIM] * INV_2PI);

    // ---- staging maps (per thread, computed once) ----
    // x tile: 64 rows x 32 floats; 4 threads per row, 8 floats per thread.
    const int xr = t >> 2;             // 0..63  local b row
    const int xc = (t & 3) * 8;        // 0,8,16,24
    const float* xrow = x + (b0 + xr) * IN_DIM + xc;
    // wg tile: 8 o x 32 i; thread -> (o_local, i).
    const int so = t >> 5;             // 0..7
    const int sj = t & 31;             // 0..31
    const float* wsrc = wfreq  + (obase + so) * LDW + sj;
    const float* gsrc = weight + (obase + so) * LDW + sj;
    const int wslot = sj * WGS + (so >> 1) * 4 + (so & 1) * 2;  // even -> b64 write

    // ---- prologue: stage chunk 0 into buffer 0 ----
    {
        const float4 a = *(const float4*)(xrow + 0);
        const float4 b = *(const float4*)(xrow + 4);
        float* d = &lx[0][xr * LXS + xc];
        d[0] = a.x * INV_2PI; d[1] = a.y * INV_2PI;
        d[2] = a.z * INV_2PI; d[3] = a.w * INV_2PI;
        d[4] = b.x * INV_2PI; d[5] = b.y * INV_2PI;
        d[6] = b.z * INV_2PI; d[7] = b.w * INV_2PI;
        wg[0][wslot]     = wsrc[0];
        wg[0][wslot + 1] = gsrc[0];
    }

    for (int c = 0; c < NCHUNK; ++c) {
        __syncthreads();   // stage(c) visible; all waves done with compute(c-1)
        const int cur = c & 1;

        // stage chunk c+1 into the other buffer (its old contents were last
        // read by compute(c-1), which the barrier above has retired).
        if (c + 1 < NCHUNK) {
            const int nxt = cur ^ 1;
            const int off = (c + 1) * CHUNK;
            const float4 a = *(const float4*)(xrow + off);
            const float4 b = *(const float4*)(xrow + off + 4);
            float* d = &lx[nxt][xr * LXS + xc];
            d[0] = a.x * INV_2PI; d[1] = a.y * INV_2PI;
            d[2] = a.z * INV_2PI; d[3] = a.w * INV_2PI;
            d[4] = b.x * INV_2PI; d[5] = b.y * INV_2PI;
            d[6] = b.z * INV_2PI; d[7] = b.w * INV_2PI;
            wg[nxt][wslot]     = wsrc[off];
            wg[nxt][wslot + 1] = gsrc[off];
        }

        // ---- compute chunk c: pure VALU + in-order DS reads ----
        const float* lxr = &lx[cur][l * LXS];   // per-lane, stride-33: conflict-free
        const float* wgr = &wg[cur][wv * 4];    // uniform addr: broadcast b128
#pragma unroll
        for (int j = 0; j < CHUNK; ++j) {
            const float4 f = *(const float4*)(wgr + j * WGS);  // {w0,g0,w1,g1}
            const float xv = lxr[j];
            acc0 = fmaf(f.y, __builtin_amdgcn_sinf(f.x * xv), acc0);
            acc1 = fmaf(f.w, __builtin_amdgcn_sinf(f.z * xv), acc1);
        }
    }

    // store: per-lane (b,o) result; 8 floats/row per block = one 32B sector.
    y[(b0 + l) * OUT_DIM + o0]     = acc0;
    y[(b0 + l) * OUT_DIM + o0 + 1] = acc1;
}

extern "C" void kernel_launch(void* const* d_in, const int* in_sizes, int n_in,
                              void* d_out, int out_size, void* d_ws, size_t ws_size,
                              hipStream_t stream) {
    const float* x      = (const float*)d_in[0];
    const float* weight = (const float*)d_in[1];
    const float* wfreq  = (const float*)d_in[2];
    float* y            = (float*)d_out;

    const int B = in_sizes[0] / IN_DIM;            // 2048
    const int grid = (B / 64) * (OUT_DIM / 8);     // 32 * 32 = 1024

    skan_kernel<<<grid, 256, 0, stream>>>(x, weight, wfreq, y);
}

// Round 2
// 77.311 us; speedup vs baseline: 1.0151x; 1.0151x over previous
//
#include <hip/hip_runtime.h>

// SKANLinear: y[b,o] = sum_{i=0}^{IN} weight[o,i] * sin(w[o,i] * x_ext[b,i])
// x_ext[b,IN] = 1.0. B=2048, IN=256, OUT=256. f32.
//
// R6: transposed decomposition. R4 (SMEM coeffs) and R5 (LDS coeffs) both
// plateaued at ~36us kernel time = coefficient-DELIVERY bound (LDS pipe per
// CU: 73k cyc of ds_read just for w/g broadcast; VALU floor is ~10us).
// Fix: lane = (b_sub[0..4), i_sub[0..16)). Each lane owns a contiguous
// 16-i run, so coefficients (2 o's x 16 i x {w,g} = 64 VGPRs) load ONCE
// and are reused across all 2048 b. Inner loop per 4-b group:
//   4x ds_read_b128 (x, transposed-staged, 80B slots = balanced banks)
//   2 o x 16 x (v_mul + v_sin + v_fma)           <- pure VALU, ~384 cyc
//   2 o x 4 DPP row_ror+add (16-lane reduction)   <- VALU pipe, not LDS
// w pre-scaled by 1/2pi at reg-load (v_sin takes revolutions), so x staging
// is a pure copy (global float4 -> ds_write_b128, double-buffered).
// LDS 10.2KB, ~110 VGPR -> 4 waves/SIMD. Grid 2048 = 8 blocks/CU.

#define IN_DIM 256
#define OUT_DIM 256
#define LDW 257
#define INV_2PI 0.15915494309189535f
#define BTILE 32
#define NBG (BTILE / 4)     // 8 groups of 4 b-rows per block
#define SLOT 20             // floats per 16-float x slot (80 B: bank-spread)

template <int CTRL>
__device__ __forceinline__ float ror_add(float v) {
    // v += rotate-within-16-lane-row(v, CTRL); after ror 1,2,4,8 every lane
    // in the row holds the full 16-lane sum. VALU pipe (no LDS).
    const int m = __builtin_amdgcn_update_dpp(0, __float_as_int(v),
                                              CTRL, 0xf, 0xf, true);
    return v + __int_as_float(m);
}

__global__ __launch_bounds__(256, 4)
void skan_kernel(const float* __restrict__ x,      // [2048][256]
                 const float* __restrict__ weight, // [256][257]
                 const float* __restrict__ wfreq,  // [256][257]
                 float* __restrict__ y)            // [2048][256]
{
    __shared__ __align__(16) float lxT[2][4 * 16 * SLOT];   // 2 x 5120 B

    const int t    = threadIdx.x;
    const int l    = t & 63;
    const int wv   = t >> 6;        // wave id 0..3
    const int isub = l & 15;        // i-run index (16 contiguous i's each)
    const int bsub = l >> 4;        // b row within 4-b group

    const int obase = (blockIdx.x & 31) * 8;       // 32 o-tiles of 8
    const int b0    = (blockIdx.x >> 5) * BTILE;   // 64 b-tiles of 32
    const int o0    = obase + wv * 2;              // wave owns o0, o0+1

    // ---- coefficients -> VGPRs, once; w scaled by 1/2pi here ----
    float wc0[16], gc0[16], wc1[16], gc1[16];
    {
        const float* wp = wfreq  + o0 * LDW + isub * 16;
        const float* gp = weight + o0 * LDW + isub * 16;
#pragma unroll
        for (int j = 0; j < 16; ++j) {
            wc0[j] = wp[j]       * INV_2PI;
            gc0[j] = gp[j];
            wc1[j] = wp[LDW + j] * INV_2PI;
            gc1[j] = gp[LDW + j];
        }
    }
    // bias column i=256 (x_ext = 1): wave-uniform, added after reduction
    const float bias0 = weight[o0 * LDW + IN_DIM] *
                        __builtin_amdgcn_sinf(wfreq[o0 * LDW + IN_DIM] * INV_2PI);
    const float bias1 = weight[(o0 + 1) * LDW + IN_DIM] *
                        __builtin_amdgcn_sinf(wfreq[(o0 + 1) * LDW + IN_DIM] * INV_2PI);

    // ---- x staging maps ----
    // read: thread t covers row (b0 + bg*4 + t>>6), floats (t&63)*4 .. +3
    //       (64 threads x 16 B = one contiguous 1 KB row per wave: coalesced)
    // write: those 4 floats land contiguously in slot (srow, i_sub=(t&63)>>2)
    //       at float offset ((t&3)*4)  -> one ds_write_b128, banks ~2-way
    const int    srow = t >> 6;
    const float* xsrc = x + (b0 + srow) * IN_DIM + (t & 63) * 4;
    const int    dsto = (srow * 16 + ((t & 63) >> 2)) * SLOT + (t & 3) * 4;
    const int    rdo  = (bsub * 16 + isub) * SLOT;   // compute-read slot base

    // prologue: stage group 0
    {
        const float4 v = *(const float4*)xsrc;
        *(float4*)&lxT[0][dsto] = v;
    }

    for (int bg = 0; bg < NBG; ++bg) {
        __syncthreads();               // stage(bg) visible to all waves
        const int cur = bg & 1;

        // my 16 x-values (contiguous i-run), 4x ds_read_b128, balanced banks
        float xv[16];
        *(float4*)&xv[0]  = *(const float4*)&lxT[cur][rdo + 0];
        *(float4*)&xv[4]  = *(const float4*)&lxT[cur][rdo + 4];
        *(float4*)&xv[8]  = *(const float4*)&lxT[cur][rdo + 8];
        *(float4*)&xv[12] = *(const float4*)&lxT[cur][rdo + 12];

        // issue next group's global load early; HBM/L2 latency hides under sin
        float4 nx;
        if (bg + 1 < NBG) nx = *(const float4*)(xsrc + (bg + 1) * 4 * IN_DIM);

        // ---- pure-VALU core: all operands in registers ----
        float a0 = 0.f, a1 = 0.f;
#pragma unroll
        for (int j = 0; j < 16; ++j) {
            const float xj = xv[j];
            a0 = fmaf(gc0[j], __builtin_amdgcn_sinf(wc0[j] * xj), a0);
            a1 = fmaf(gc1[j], __builtin_amdgcn_sinf(wc1[j] * xj), a1);
        }

        // write next group into the other buffer (its last readers finished
        // before this iteration's barrier)
        if (bg + 1 < NBG) *(float4*)&lxT[cur ^ 1][dsto] = nx;

        // 16-lane i_sub reduction on the VALU pipe (DPP), per o
        a0 = ror_add<0x121>(a0); a0 = ror_add<0x122>(a0);
        a0 = ror_add<0x124>(a0); a0 = ror_add<0x128>(a0);
        a1 = ror_add<0x121>(a1); a1 = ror_add<0x122>(a1);
        a1 = ror_add<0x124>(a1); a1 = ror_add<0x128>(a1);

        // every lane in a 16-row now holds the full sum; lanes isub<2 store
        if (isub < 2) {
            const float out = (isub == 0) ? a0 + bias0 : a1 + bias1;
            y[(b0 + bg * 4 + bsub) * OUT_DIM + o0 + isub] = out;
        }
    }
}

extern "C" void kernel_launch(void* const* d_in, const int* in_sizes, int n_in,
                              void* d_out, int out_size, void* d_ws, size_t ws_size,
                              hipStream_t stream) {
    const float* x      = (const float*)d_in[0];
    const float* weight = (const float*)d_in[1];
    const float* wfreq  = (const float*)d_in[2];
    float* y            = (float*)d_out;

    const int B = in_sizes[0] / IN_DIM;                 // 2048
    const int grid = (B / BTILE) * (OUT_DIM / 8);       // 64 * 32 = 2048

    skan_kernel<<<grid, 256, 0, stream>>>(x, weight, wfreq, y);
}